// Round 1
// baseline (978.455 us; speedup 1.0000x reference)
//
#include <hip/hip_runtime.h>
#include <math.h>

#define B_ 32
#define N_ 2048
#define ROWS_PER_BLOCK 16   // 4 waves * 4 rows each
#define BLOCKS_PER_BATCH (N_ / ROWS_PER_BLOCK)

// ---------------- Kernel A: per-batch scale = -(L^2)*(1 - mean(|x|^2)) -----
__global__ __launch_bounds__(256) void scale_kernel(const float* __restrict__ x_r,
                                                    const float* __restrict__ x_i,
                                                    float* __restrict__ scale) {
    const int b = blockIdx.x;
    const int t = threadIdx.x;
    const float* xr = x_r + (size_t)b * N_;
    const float* xi = x_i + (size_t)b * N_;
    float s = 0.f;
    for (int i = t; i < N_; i += 256) {
        float a = xr[i], c = xi[i];
        s += a * a + c * c;
    }
    #pragma unroll
    for (int m = 1; m < 64; m <<= 1) s += __shfl_xor(s, m, 64);
    __shared__ float parts[4];
    if ((t & 63) == 0) parts[t >> 6] = s;
    __syncthreads();
    if (t == 0) {
        float tot = parts[0] + parts[1] + parts[2] + parts[3];
        scale[b] = -2.25f * (1.0f - tot / (float)N_);   // L = 1.5, L^2 = 2.25
    }
}

// ---------------- Kernel B: fused complex matvec + epilogue ----------------
__global__ __launch_bounds__(256) void sync_block_kernel(
    const float* __restrict__ Yr, const float* __restrict__ Yi,
    const float* __restrict__ x_r, const float* __restrict__ x_i,
    const float* __restrict__ xp_r, const float* __restrict__ xp_i,
    const float* __restrict__ d3w, const float* __restrict__ d3b,
    const float* __restrict__ w1, const float* __restrict__ b1,
    const float* __restrict__ w2, const float* __restrict__ b2,
    const float* __restrict__ scale, float* __restrict__ out)
{
    __shared__ float4 xs_r[N_ / 4];
    __shared__ float4 xs_i[N_ / 4];

    const int t    = threadIdx.x;
    const int lane = t & 63;
    const int wave = t >> 6;
    const int b    = blockIdx.x / BLOCKS_PER_BATCH;
    const int row0 = (blockIdx.x % BLOCKS_PER_BATCH) * ROWS_PER_BLOCK;

    // stage x_r, x_i for this batch into LDS (reused by all 16 rows)
    const float4* gxr = (const float4*)(x_r + (size_t)b * N_);
    const float4* gxi = (const float4*)(x_i + (size_t)b * N_);
    for (int i = t; i < N_ / 4; i += 256) {
        xs_r[i] = gxr[i];
        xs_i[i] = gxi[i];
    }
    __syncthreads();

    // hoist MLP weights: 4 hidden units per lane (lane, lane+64, +128, +192)
    float w1v[4], b1v[4], w2v[4];
    #pragma unroll
    for (int k = 0; k < 4; ++k) {
        w1v[k] = w1[lane + 64 * k];
        b1v[k] = b1[lane + 64 * k];
        w2v[k] = w2[lane + 64 * k];
    }
    const float d3w_v = d3w[0], d3b_v = d3b[0], b2v = b2[0];
    const float sc = scale[b];

    #pragma unroll
    for (int r = 0; r < 4; ++r) {
        const int row = row0 + wave * 4 + r;
        const float4* yr4 = (const float4*)(Yr + ((size_t)b * N_ + row) * (size_t)N_);
        const float4* yi4 = (const float4*)(Yi + ((size_t)b * N_ + row) * (size_t)N_);

        float rr = 0.f, ri = 0.f, ir = 0.f, ii = 0.f;
        #pragma unroll
        for (int it = 0; it < 8; ++it) {
            const int idx = lane + it * 64;
            float4 a = yr4[idx];
            float4 c = yi4[idx];
            float4 u = xs_r[idx];
            float4 v = xs_i[idx];
            rr += a.x * u.x + a.y * u.y + a.z * u.z + a.w * u.w;
            ri += a.x * v.x + a.y * v.y + a.z * v.z + a.w * v.w;
            ir += c.x * u.x + c.y * u.y + c.z * u.z + c.w * u.w;
            ii += c.x * v.x + c.y * v.y + c.z * v.z + c.w * v.w;
        }
        // 64-lane butterfly reduce; all lanes end with the full sums
        #pragma unroll
        for (int m = 1; m < 64; m <<= 1) {
            rr += __shfl_xor(rr, m, 64);
            ri += __shfl_xor(ri, m, 64);
            ir += __shfl_xor(ir, m, 64);
            ii += __shfl_xor(ii, m, 64);
        }

        float x1r = 1.5f * (rr - ii);
        float x1i = 1.5f * (ri + ir);
        // Dense(1): x @ d3_w + d3_b (trailing dim 1 -> scalar affine)
        x1r = x1r * d3w_v + d3b_v;
        x1i = x1i * d3w_v + d3b_v;
        // + scale * x_prev
        x1r += sc * xp_r[(size_t)b * N_ + row];
        x1i += sc * xp_i[(size_t)b * N_ + row];

        const float xabs  = sqrtf(x1r * x1r + x1i * x1i);
        const float denom = fmaxf(xabs, 1e-12f);

        // MLP 1->256->1: each lane handles 4 hidden units, butterfly-reduce
        float p = 0.f;
        #pragma unroll
        for (int k = 0; k < 4; ++k) {
            float h = fmaxf(xabs * w1v[k] + b1v[k], 0.f);
            p += h * w2v[k];
        }
        #pragma unroll
        for (int m = 1; m < 64; m <<= 1) p += __shfl_xor(p, m, 64);

        const float g = tanhf(p + b2v);
        const float q = g / denom;

        if (lane == 0) {
            out[(size_t)b * N_ + row]                    = x1r * q;
            out[(size_t)B_ * N_ + (size_t)b * N_ + row]  = x1i * q;
        }
    }
}

extern "C" void kernel_launch(void* const* d_in, const int* in_sizes, int n_in,
                              void* d_out, int out_size, void* d_ws, size_t ws_size,
                              hipStream_t stream) {
    const float* Yr   = (const float*)d_in[0];
    const float* Yi   = (const float*)d_in[1];
    const float* x_r  = (const float*)d_in[2];
    const float* x_i  = (const float*)d_in[3];
    const float* xp_r = (const float*)d_in[4];
    const float* xp_i = (const float*)d_in[5];
    const float* d3w  = (const float*)d_in[6];
    const float* d3b  = (const float*)d_in[7];
    const float* w1   = (const float*)d_in[8];
    const float* b1   = (const float*)d_in[9];
    const float* w2   = (const float*)d_in[10];
    const float* b2   = (const float*)d_in[11];
    float* out   = (float*)d_out;
    float* scale = (float*)d_ws;   // 32 floats

    scale_kernel<<<B_, 256, 0, stream>>>(x_r, x_i, scale);
    sync_block_kernel<<<(B_ * N_) / ROWS_PER_BLOCK, 256, 0, stream>>>(
        Yr, Yi, x_r, x_i, xp_r, xp_i, d3w, d3b, w1, b1, w2, b2, scale, out);
}